// Round 8
// baseline (290.567 us; speedup 1.0000x reference)
//
#include <hip/hip_runtime.h>
#include <math.h>

#define BB 32
#define NN 2048
#define D_IN 320
#define H1 160
#define H2 80
#define H4 5

typedef __attribute__((ext_vector_type(8))) short short8;
typedef __attribute__((ext_vector_type(4))) short short4v;
typedef __attribute__((ext_vector_type(4))) float f32x4;
typedef __attribute__((ext_vector_type(16))) float f32x16;

__device__ inline ushort f2bf(float f) {
    union { float f; unsigned u; } v; v.f = f;
    unsigned r = v.u + 0x7fff + ((v.u >> 16) & 1);   // RNE
    return (ushort)(r >> 16);
}
__device__ inline float bf2f(ushort u) {
    union { float f; unsigned u; } v; v.u = ((unsigned)u) << 16;
    return v.f;
}
// pack 2 floats -> 2 bf16 in one dword (lo in low half): round-half-up + v_perm
__device__ inline unsigned pkbf(float hi, float lo) {
    union { float f; unsigned u; } a, b; a.f = hi; b.f = lo;
    return __builtin_amdgcn_perm(a.u + 0x8000u, b.u + 0x8000u, 0x07060302u);
}
// bare v_exp_f32: args here are always <= 0; big-negative flushes to 0 (wanted).
__device__ inline float fexp2(float x) {
    float r;
    asm("v_exp_f32 %0, %1" : "=v"(r) : "v"(x));
    return r;
}
union U2S { unsigned u[2]; short4v s; };
union U4S { unsigned u[4]; short8 s; short4v h[2]; };

#define LOG2E  1.44269504088896340736f
#define TWOL2E 2.88539008177792681472f

// ---------------------------------------------------------------------------
// Prep: bf16-transpose weights. Wt1[160][320], Wt2[80][160] (MLP B-operands).
// Wg1B[48][96]: plain B-operand layout for the mlp-epilogue V1' projection.
// Wg2A[32][48]: A-operand layout, phi-permuted, for the combine-epilogue V2'.
// bg1P[64], bg2P[32] zero-padded.
// ---------------------------------------------------------------------------
__global__ __launch_bounds__(256) void prep_weights_kernel(
    const float* __restrict__ W1, const float* __restrict__ W2,
    const float* __restrict__ Wg1, const float* __restrict__ bg1,
    const float* __restrict__ Wg2, const float* __restrict__ bg2,
    ushort* __restrict__ Wt1, ushort* __restrict__ Wt2,
    ushort* __restrict__ Wg1B, float* __restrict__ bg1P,
    ushort* __restrict__ Wg2A, float* __restrict__ bg2P)
{
    const int id0 = blockIdx.x * 256 + threadIdx.x;
    const int stride = gridDim.x * 256;
    for (int i = id0; i < H1 * D_IN; i += stride) {
        const int j = i / D_IN, c = i % D_IN;
        Wt1[i] = f2bf(W1[c * H1 + j]);
    }
    for (int i = id0; i < H2 * H1; i += stride) {
        const int j = i / H1, c = i % H1;
        Wt2[i] = f2bf(W2[c * H2 + j]);
    }
    for (int i = id0; i < 48 * 96; i += stride) {
        const int j = i / 96, c = i % 96;
        Wg1B[i] = (j < 40 && c < 80) ? f2bf(Wg1[c * 40 + j]) : (ushort)0;
    }
    for (int i = id0; i < 32 * 48; i += stride) {
        const int j = i / 48, c = i % 48;
        const int c4 = c & 15;
        const int pos = (c & ~15) + (c4 & 3) + (((c4 >> 3) & 1) << 2) + (((c4 >> 2) & 1) << 3);
        Wg2A[j * 48 + pos] = (j < 5 && c < 40) ? f2bf(Wg2[c * 5 + j]) : (ushort)0;
    }
    if (id0 < 64) bg1P[id0] = (id0 < 40) ? bg1[id0] : 0.f;
    if (id0 < 32) bg2P[id0] = (id0 < 5) ? bg2[id0] : 0.f;
}

// ---------------------------------------------------------------------------
// MFMA MLP: h2 = relu(relu(x@W1+b1)@W2+b2), XCD-swizzled.
// Computes the FOLDED conv1 value tensor V1' = h2 @ Wg1 -> V1T [b][48][N].
// h2 stored UNSCALED; sq2 = 0.5*|h2_bf16|^2 from the exact stored bits.
// ---------------------------------------------------------------------------
__global__ __launch_bounds__(256) void mlp_mfma_kernel(
    const float* __restrict__ x,
    const ushort* __restrict__ Wt1, const float* __restrict__ b1,
    const ushort* __restrict__ Wt2, const float* __restrict__ b2,
    const ushort* __restrict__ Wg1B,
    ushort* __restrict__ h2, ushort* __restrict__ V1T, float* __restrict__ sq2)
{
    constexpr int XST  = 72;
    constexpr int W1ST = 72;
    constexpr int H1ST = 168;
    constexpr int RST  = 104;   // h2 row-major stride for V1' A-frags

    __shared__ __attribute__((aligned(16))) ushort h1t[64 * H1ST];  // aliases xs
    __shared__ __attribute__((aligned(16))) ushort ws1[H1 * W1ST];  // aliases Tbuf
    __shared__ float b1s[H1];
    __shared__ float b2s[H2];

    ushort* xs = h1t;

    const int t = threadIdx.x;
    const int lane = t & 63, w = t >> 6;
    const int colid = lane & 15, quad = lane >> 4;
    const int i = blockIdx.x;
    const int b = ((i & 7) << 2) + ((i >> 3) & 3);
    const int n0 = (i >> 5) * 64;
    const int row0 = b * NN + n0;

    if (t < H1) b1s[t] = b1[t];
    if (t < H2) b2s[t] = b2[t];

    f32x4 c1[10];
    #pragma unroll
    for (int ns = 0; ns < 10; ++ns) c1[ns] = (f32x4){0.f, 0.f, 0.f, 0.f};

    float4 xr[4];
    short8 wr[5];
    {
        #pragma unroll
        for (int i2 = 0; i2 < 4; ++i2) {
            const int id = t + i2 * 256, row = id >> 4, c4 = id & 15;
            xr[i2] = *(const float4*)&x[(size_t)(row0 + row) * D_IN + c4 * 4];
        }
        #pragma unroll
        for (int i2 = 0; i2 < 5; ++i2) {
            const int id = t + i2 * 256, j = id >> 3, part = id & 7;
            wr[i2] = *(const short8*)&Wt1[j * D_IN + part * 8];
        }
    }

    for (int kc = 0; kc < 5; ++kc) {
        if (kc) __syncthreads();
        #pragma unroll
        for (int i2 = 0; i2 < 4; ++i2) {
            const int id = t + i2 * 256, row = id >> 4, c4 = id & 15;
            uint2 up;
            up.x = pkbf(xr[i2].y, xr[i2].x);
            up.y = pkbf(xr[i2].w, xr[i2].z);
            *(uint2*)&xs[row * XST + c4 * 4] = up;
        }
        #pragma unroll
        for (int i2 = 0; i2 < 5; ++i2) {
            const int id = t + i2 * 256, j = id >> 3, part = id & 7;
            *(short8*)&ws1[j * W1ST + part * 8] = wr[i2];
        }
        __syncthreads();
        if (kc < 4) {
            const int k0 = (kc + 1) * 64;
            #pragma unroll
            for (int i2 = 0; i2 < 4; ++i2) {
                const int id = t + i2 * 256, row = id >> 4, c4 = id & 15;
                xr[i2] = *(const float4*)&x[(size_t)(row0 + row) * D_IN + k0 + c4 * 4];
            }
            #pragma unroll
            for (int i2 = 0; i2 < 5; ++i2) {
                const int id = t + i2 * 256, j = id >> 3, part = id & 7;
                wr[i2] = *(const short8*)&Wt1[j * D_IN + k0 + part * 8];
            }
        }

        short8 af[2];
        #pragma unroll
        for (int kf = 0; kf < 2; ++kf)
            af[kf] = *(const short8*)&xs[(w * 16 + colid) * XST + kf * 32 + quad * 8];
        #pragma unroll
        for (int ns = 0; ns < 10; ++ns) {
            #pragma unroll
            for (int kf = 0; kf < 2; ++kf) {
                const short8 bf = *(const short8*)&ws1[(ns * 16 + colid) * W1ST + kf * 32 + quad * 8];
                c1[ns] = __builtin_amdgcn_mfma_f32_16x16x32_bf16(af[kf], bf, c1[ns], 0, 0, 0);
            }
        }
    }
    __syncthreads();                            // xs dead -> h1t reuse

    #pragma unroll
    for (int ns = 0; ns < 10; ++ns) {
        const float bj = b1s[ns * 16 + colid];
        #pragma unroll
        for (int r = 0; r < 4; ++r)
            h1t[(w * 16 + quad * 4 + r) * H1ST + ns * 16 + colid] =
                f2bf(fmaxf(c1[ns][r] + bj, 0.f));
    }
    __asm__ volatile("s_waitcnt lgkmcnt(0)" ::: "memory");  // wave-private rows

    short8 a2[5];
    #pragma unroll
    for (int kf = 0; kf < 5; ++kf)
        a2[kf] = *(const short8*)&h1t[(w * 16 + colid) * H1ST + kf * 32 + quad * 8];

    f32x4 c2[5];
    #pragma unroll
    for (int js = 0; js < 5; ++js) {
        f32x4 acc = (f32x4){0.f, 0.f, 0.f, 0.f};
        #pragma unroll
        for (int kf = 0; kf < 5; ++kf) {
            const short8 wb = *(const short8*)&Wt2[(js * 16 + colid) * H1 + kf * 32 + quad * 8];
            acc = __builtin_amdgcn_mfma_f32_16x16x32_bf16(a2[kf], wb, acc, 0, 0, 0);
        }
        c2[js] = acc;
    }
    __syncthreads();                            // h1t(a2 reads)/ws1 dead

    // ---- epilogue: h2 global (unscaled) + row-major LDS copy, rsq ----
    ushort* h2row = h1t;                        // [64][RST] row-major
    float rsq[4] = {0.f, 0.f, 0.f, 0.f};
    #pragma unroll
    for (int js = 0; js < 5; ++js) {
        const float bj = b2s[js * 16 + colid];
        #pragma unroll
        for (int r = 0; r < 4; ++r) {
            const ushort u = f2bf(fmaxf(c2[js][r] + bj, 0.f));
            const float vv = bf2f(u);
            rsq[r] += vv * vv;
            h2[(size_t)(row0 + w * 16 + quad * 4 + r) * 80 + js * 16 + colid] = u;
            h2row[(w * 16 + quad * 4 + r) * RST + js * 16 + colid] = u;
        }
    }
    {   // zero cols 80..95 (wave-private rows: t>>2 in [w*16, w*16+16))
        const int zr = t >> 2, zc = t & 3;
        *(short4v*)&h2row[zr * RST + 80 + zc * 4] = (short4v){0, 0, 0, 0};
    }
    __asm__ volatile("s_waitcnt lgkmcnt(0)" ::: "memory");  // wave-private rows

    // ---- V1' = h2 @ Wg1 (48 out, k padded to 96; Wg1B zero kills pad) ----
    short8 a3[3];
    #pragma unroll
    for (int kf = 0; kf < 3; ++kf)
        a3[kf] = *(const short8*)&h2row[(w * 16 + colid) * RST + kf * 32 + quad * 8];

    f32x4 c3[3];
    #pragma unroll
    for (int js = 0; js < 3; ++js) {
        f32x4 acc = (f32x4){0.f, 0.f, 0.f, 0.f};
        #pragma unroll
        for (int kf = 0; kf < 3; ++kf) {
            const short8 wb = *(const short8*)&Wg1B[(js * 16 + colid) * 96 + kf * 32 + quad * 8];
            acc = __builtin_amdgcn_mfma_f32_16x16x32_bf16(a3[kf], wb, acc, 0, 0, 0);
        }
        c3[js] = acc;
    }

    #pragma unroll
    for (int m = 1; m <= 8; m <<= 1)
        #pragma unroll
        for (int r = 0; r < 4; ++r) rsq[r] += __shfl_xor(rsq[r], m);
    if (colid == 0) {
        #pragma unroll
        for (int r = 0; r < 4; ++r)
            sq2[(size_t)row0 + w * 16 + quad * 4 + r] = rsq[r] * 0.5f;
    }

    // ---- transpose V1' -> V1T [b][48][N], ones row at 40 ----
    ushort* Tbuf = ws1;                         // [48][72]
    #pragma unroll
    for (int js = 0; js < 3; ++js)
        #pragma unroll
        for (int r = 0; r < 4; ++r)
            Tbuf[(js * 16 + colid) * 72 + w * 16 + quad * 4 + r] = f2bf(c3[js][r]);
    __syncthreads();
    const short8 ones8 = {16256, 16256, 16256, 16256, 16256, 16256, 16256, 16256};
    for (int id = t; id < 48 * 8; id += 256) {
        const int row = id >> 3, part = id & 7;
        const short8 val = (row == 40) ? ones8 : *(const short8*)&Tbuf[row * 72 + part * 8];
        *(short8*)&V1T[((size_t)b * 48 + row) * NN + n0 + part * 8] = val;
    }
}

// ---------------------------------------------------------------------------
// Flash-attention graph conv, PARTIAL pass. K-SPLIT ACROSS BLOCKS: grid =
// 512 q-tiles x KSPLIT key-halves, 256-thread blocks (4 waves x 32 q).
// Block (qblk, ks) accumulates partial O over keys [ks*1024,(ks+1)*1024)
// with the R7-proven inner loop (CVS-only staging, double-buffered LDS =
// 36.9/19.5 KB -> 4+ blocks/CU co-resident; barriers are block-local so
// independent blocks hide each other's drains). Partial fp32 O written
// coalesced to pO; a combine kernel sums halves and runs the epilogue.
// Exponential weights additive (fixed seed) -> exact split (R7-proven).
// S accumulator seeded with -0.5|q|^2-0.5|k|^2; p = exp2(st * 2log2e).
// ---------------------------------------------------------------------------
template<int CK, int CV, int CVS, int KSPLIT>
__global__ __launch_bounds__(256, 2) void attn_part_kernel(
    const ushort* __restrict__ h, const ushort* __restrict__ hT,
    const float* __restrict__ sqg, float* __restrict__ pO)
{
    constexpr int CF   = CK / 16;        // S-phase k-chunks (5 / 3)
    constexpr int CSV  = CV / 32;        // PV channel tiles (2 / 1)
    constexpr int KST  = CK + 8;         // 88 / 56
    constexpr int VST  = 64 + 8;         // 72
    constexpr int KPR  = CK / 8;
    constexpr int KTOT = 64 * KPR;
    constexpr int NK   = (KTOT + 255) / 256;
    constexpr int VTOT = CVS * 8;        // staged V rows only (48/16)
    constexpr int NV   = (VTOT + 255) / 256;
    constexpr int BUFN = 64 * KST + CVS * VST;
    constexpr int NITH = NN / 64 / KSPLIT;   // 16 key tiles per half

    __shared__ __attribute__((aligned(16))) ushort ldsbuf[2][BUFN];
    __shared__ __attribute__((aligned(16))) float sqs[2][64];

    const int t = threadIdx.x;
    const int lane = t & 63, w = t >> 6;
    const int m32 = lane & 31, hl = lane >> 5;
    const int gi = blockIdx.x;
    const int ks = gi & (KSPLIT - 1);
    const int qblk = gi / KSPLIT;
    const int b = ((qblk & 7) << 2) + ((qblk >> 3) & 3);
    const int n0blk = (qblk >> 5) * 128;
    const int qrow = n0blk + w * 32 + m32;
    const int kbase = ks * (NN / KSPLIT);

    // Q B-operand frags
    short8 qf[CF];
    {
        const ushort* qr = h + ((size_t)b * NN + qrow) * CK;
        #pragma unroll
        for (int c = 0; c < CF; ++c)
            qf[c] = *(const short8*)&qr[c * 16 + hl * 8];
    }
    const float nsqn = -sqg[(size_t)b * NN + qrow];   // = -0.5|q|^2

    f32x16 o[CSV];
    #pragma unroll
    for (int cs = 0; cs < CSV; ++cs)
        #pragma unroll
        for (int r = 0; r < 16; ++r) o[cs][r] = 0.f;

    short8 kreg[NK], vreg[NV];
    float sqreg = 0.f;

    auto loadTile = [&](int n1) {
        const ushort* hsrc = h + ((size_t)b * NN + n1) * CK;
        #pragma unroll
        for (int i2 = 0; i2 < NK; ++i2) {
            const int id = t + i2 * 256;
            if (KTOT % 256 == 0 || id < KTOT)
                kreg[i2] = *(const short8*)&hsrc[id * 8];
        }
        #pragma unroll
        for (int i2 = 0; i2 < NV; ++i2) {
            const int id = t + i2 * 256;
            if (VTOT % 256 == 0 || id < VTOT) {
                const int c = id >> 3, pt = id & 7;
                vreg[i2] = *(const short8*)&hT[((size_t)b * CVS + c) * NN + n1 + pt * 8];
            }
        }
        if (t < 64) sqreg = sqg[(size_t)b * NN + n1 + t];
    };
    auto stageTile = [&](int buf) {
        ushort* Kd = ldsbuf[buf];
        ushort* Vd = Kd + 64 * KST;
        #pragma unroll
        for (int i2 = 0; i2 < NK; ++i2) {
            const int id = t + i2 * 256;
            if (KTOT % 256 == 0 || id < KTOT) {
                const int row = id / KPR, pt = id % KPR;
                *(short8*)&Kd[row * KST + pt * 8] = kreg[i2];
            }
        }
        #pragma unroll
        for (int i2 = 0; i2 < NV; ++i2) {
            const int id = t + i2 * 256;
            if (VTOT % 256 == 0 || id < VTOT) {
                const int c = id >> 3, pt = id & 7;
                const int colb = ((pt >> 1) << 4) + ((pt & 1) << 2);  // phi baked in
                U4S vv; vv.s = vreg[i2];
                *(short4v*)&Vd[c * VST + colb]     = vv.h[0];
                *(short4v*)&Vd[c * VST + colb + 8] = vv.h[1];
            }
        }
        if (t < 64) sqs[buf][t] = sqreg;
    };

    auto preloadK = [&](const ushort* Krow, short8 (&kf)[2][CF]) {
        #pragma unroll
        for (int T = 0; T < 2; ++T)
            #pragma unroll
            for (int c = 0; c < CF; ++c)
                kf[T][c] = *(const short8*)&Krow[(T * 32 + m32) * KST + c * 16 + hl * 8];
    };
    auto initST = [&](int buf, f32x16& s0, f32x16& s1) {
        #pragma unroll
        for (int g = 0; g < 4; ++g) {
            const f32x4 sm0 = *(const f32x4*)&sqs[buf][g * 8 + hl * 4];
            const f32x4 sm1 = *(const f32x4*)&sqs[buf][32 + g * 8 + hl * 4];
            #pragma unroll
            for (int r2 = 0; r2 < 4; ++r2) {
                s0[g * 4 + r2] = nsqn - sm0[r2];
                s1[g * 4 + r2] = nsqn - sm1[r2];
            }
        }
    };
    auto smfma = [&](short8 (&kf)[2][CF], f32x16& s0, f32x16& s1) {
        #pragma unroll
        for (int c = 0; c < CF; ++c) {
            s0 = __builtin_amdgcn_mfma_f32_32x32x16_bf16(kf[0][c], qf[c], s0, 0, 0, 0);
            s1 = __builtin_amdgcn_mfma_f32_32x32x16_bf16(kf[1][c], qf[c], s1, 0, 0, 0);
        }
    };
    auto readV = [&](const ushort* Vcol, short8 (&vf)[2][2][CSV]) {
        const short8 z8 = {0, 0, 0, 0, 0, 0, 0, 0};
        #pragma unroll
        for (int T = 0; T < 2; ++T)
            #pragma unroll
            for (int c = 0; c < 2; ++c)
                #pragma unroll
                for (int cs = 0; cs < CSV; ++cs) {
                    const int row = cs * 32 + m32;
                    vf[T][c][cs] = (row < CVS)
                        ? *(const short8*)&Vcol[row * VST + (T * 2 + c) * 16 + hl * 8]
                        : z8;
                }
    };
    auto expPV = [&](const f32x16& s0, const f32x16& s1, const short8 (&vf)[2][2][CSV]) {
        #pragma unroll
        for (int T = 0; T < 2; ++T) {
            const f32x16& st = T ? s1 : s0;
            float p[16];
            #pragma unroll
            for (int g = 0; g < 4; ++g)
                #pragma unroll
                for (int r2 = 0; r2 < 4; ++r2)
                    p[g * 4 + r2] = fexp2(st[g * 4 + r2] * TWOL2E);
            #pragma unroll
            for (int c = 0; c < 2; ++c) {
                U4S pk_;
                #pragma unroll
                for (int bq = 0; bq < 4; ++bq)
                    pk_.u[bq] = pkbf(p[c * 8 + bq * 2 + 1], p[c * 8 + bq * 2]);
                #pragma unroll
                for (int cs = 0; cs < CSV; ++cs)
                    o[cs] = __builtin_amdgcn_mfma_f32_32x32x16_bf16(vf[T][c][cs], pk_.s, o[cs], 0, 0, 0);
            }
        }
    };

    // prologue: tile kbase staged; tile kbase+64 in regs
    loadTile(kbase);
    stageTile(0);
    __syncthreads();
    loadTile(kbase + 64);

    #pragma unroll 1
    for (int it = 0; it < NITH; ++it) {
        const int cur = it & 1;
        const ushort* Krow = ldsbuf[cur];
        const ushort* Vcol = Krow + 64 * KST;

        short8 kf[2][CF];
        f32x16 s0, s1;
        preloadK(Krow, kf);
        initST(cur, s0, s1);

        if (it + 1 < NITH) stageTile(cur ^ 1);           // tile it+1 (regs)
        if (it + 2 < NITH) loadTile(kbase + (it + 2) * 64);

        smfma(kf, s0, s1);
        short8 vf[2][2][CSV];
        readV(Vcol, vf);
        expPV(s0, s1, vf);
        __syncthreads();
    }

    // ---- write partial O, coalesced (256 consecutive floats per reg) ----
    #pragma unroll
    for (int cs = 0; cs < CSV; ++cs)
        #pragma unroll
        for (int r = 0; r < 16; ++r)
            pO[((((size_t)qblk * KSPLIT + ks) * CSV + cs) * 16 + r) * 256 + t] = o[cs][r];
}

// ---------------------------------------------------------------------------
// Combine: sum KSPLIT partial O's (fp32, same order as R7's LDS exchange ->
// bit-identical), then the R7 epilogue: denominator from ones channel,
// h3 = relu(O/denom + b) + sq3 + V2' = h3@Wg2 -> V2T (conv1), or mean (conv2).
// ---------------------------------------------------------------------------
template<int CV, int CVS, int ONES_CH, bool HAS_OUT, bool DO_MEAN, int C_OUT, int KSPLIT>
__global__ __launch_bounds__(256) void attn_combine_kernel(
    const float* __restrict__ pO,
    const ushort* __restrict__ WtP, const float* __restrict__ biasP,
    ushort* __restrict__ ho, ushort* __restrict__ hoT, float* __restrict__ sqo,
    float* __restrict__ mean_out)
{
    constexpr int CSV = CV / 32;
    constexpr int TST = 136;
    constexpr int CS1 = ONES_CH / 32;
    constexpr int R1v = ((ONES_CH % 32) / 8) * 4 + (ONES_CH & 3);

    __shared__ __attribute__((aligned(16))) ushort Tbuf[16 * TST];

    const int t = threadIdx.x;
    const int lane = t & 63, w = t >> 6;
    const int m32 = lane & 31, hl = lane >> 5;
    const int i = blockIdx.x;
    const int b = ((i & 7) << 2) + ((i >> 3) & 3);
    const int n0blk = (i >> 5) * 128;
    const int qrow = n0blk + w * 32 + m32;

    f32x16 o[CSV];
    #pragma unroll
    for (int cs = 0; cs < CSV; ++cs)
        #pragma unroll
        for (int r = 0; r < 16; ++r) o[cs][r] = 0.f;
    #pragma unroll
    for (int ks = 0; ks < KSPLIT; ++ks)
        #pragma unroll
        for (int cs = 0; cs < CSV; ++cs)
            #pragma unroll
            for (int r = 0; r < 16; ++r)
                o[cs][r] += pO[((((size_t)i * KSPLIT + ks) * CSV + cs) * 16 + r) * 256 + t];

    // denominator from the ones-channel accumulator (lane hl=0 holds it)
    float rsv = (hl == 0) ? o[CS1][R1v] : 0.f;
    rsv += __shfl_xor(rsv, 32);
    const float rinv = 1.f / rsv;

    if constexpr (DO_MEAN) {
        // channels 0..3 live at hl=0 regs 0..3; channel 4 at hl=1 reg 0
        float msum[4];
        #pragma unroll
        for (int r2 = 0; r2 < 4; ++r2)
            msum[r2] = fmaxf(o[0][r2] * rinv + biasP[hl * 4 + r2], 0.f);
        #pragma unroll
        for (int s = 1; s <= 16; s <<= 1)
            #pragma unroll
            for (int r2 = 0; r2 < 4; ++r2) msum[r2] += __shfl_xor(msum[r2], s);
        if (m32 == 0) {
            if (hl == 0) {
                #pragma unroll
                for (int r2 = 0; r2 < 4; ++r2)
                    atomicAdd(&mean_out[b * C_OUT + r2], msum[r2] * (1.f / NN));
            } else {
                atomicAdd(&mean_out[b * C_OUT + 4], msum[0] * (1.f / NN));
            }
        }
    }

    if constexpr (HAS_OUT) {
        // O is ALREADY projected (40 ch). h3 = relu(O*rinv + b); zero pads.
        float vv[CSV][16];
        float rsq = 0.f;
        #pragma unroll
        for (int cs = 0; cs < CSV; ++cs) {
            #pragma unroll
            for (int g = 0; g < 4; ++g) {
                const int jb = cs * 32 + g * 8 + hl * 4;
                const f32x4 bv = *(const f32x4*)&biasP[jb];
                float v[4];
                #pragma unroll
                for (int r2 = 0; r2 < 4; ++r2) {
                    float val = fmaxf(o[cs][g * 4 + r2] * rinv + bv[r2], 0.f);
                    if (cs == CS1 && g * 4 + r2 == R1v) val = 0.f;  // ones slot
                    v[r2] = val;
                    vv[cs][g * 4 + r2] = val;
                }
                if (jb < 48) {                 // h3 stored at stride 48
                    U2S uo;
                    uo.u[0] = pkbf(v[1], v[0]);
                    uo.u[1] = pkbf(v[3], v[2]);
                    *(short4v*)&ho[((size_t)b * NN + qrow) * 48 + jb] = uo.s;
                    #pragma unroll
                    for (int r2 = 0; r2 < 4; ++r2) {
                        const float vs = bf2f((ushort)(uo.u[r2 >> 1] >> ((r2 & 1) * 16)));
                        rsq += vs * vs;
                    }
                }
            }
        }
        const float rsq2 = rsq + __shfl_xor(rsq, 32);
        if (hl == 0) sqo[(size_t)b * NN + qrow] = rsq2 * 0.5f;

        // V2' = h3 @ Wg2 (phi-consistent frags)
        short8 ob2[3];
        #pragma unroll
        for (int cc = 0; cc < 3; ++cc) {
            const int cs = cc >> 1, c2 = cc & 1;
            U4S ob_;
            #pragma unroll
            for (int bq = 0; bq < 4; ++bq)
                ob_.u[bq] = pkbf(vv[cs][c2 * 8 + bq * 2 + 1], vv[cs][c2 * 8 + bq * 2]);
            ob2[cc] = ob_.s;
        }
        f32x16 acc;
        #pragma unroll
        for (int r = 0; r < 16; ++r) acc[r] = 0.f;
        #pragma unroll
        for (int cc = 0; cc < 3; ++cc) {
            const short8 wa = *(const short8*)&WtP[(size_t)m32 * 48 + cc * 16 + hl * 8];
            acc = __builtin_amdgcn_mfma_f32_32x32x16_bf16(wa, ob2[cc], acc, 0, 0, 0);
        }

        // transposed store: V2T[b][16][n]; rows 0..4 = V2', 8 = ones, rest 0
        #pragma unroll
        for (int g = 0; g < 2; ++g)
            #pragma unroll
            for (int r2 = 0; r2 < 4; ++r2)
                Tbuf[(g * 8 + hl * 4 + r2) * TST + w * 32 + m32] = f2bf(acc[g * 4 + r2]);
        __syncthreads();
        const short8 ones8 = {16256, 16256, 16256, 16256, 16256, 16256, 16256, 16256};
        {
            const int row = t >> 4, part = t & 15;   // 16 rows x 16 parts = 256
            const short8 val = (row == 8) ? ones8
                             : *(const short8*)&Tbuf[row * TST + part * 8];
            *(short8*)&hoT[((size_t)b * 16 + row) * NN + n0blk + part * 8] = val;
        }
    }
}

// ---------------------------------------------------------------------------
// Final classifier + softmax over 2 logits.
// ---------------------------------------------------------------------------
__global__ __launch_bounds__(64) void final_kernel(
    const float* __restrict__ mean, const float* __restrict__ Wf,
    const float* __restrict__ bf, float* __restrict__ out)
{
    const int t = threadIdx.x;
    const int b = t >> 1, k = t & 1;
    float acc = bf[k];
    #pragma unroll
    for (int c = 0; c < H4; ++c) acc += mean[b * H4 + c] * Wf[c * 2 + k];
    const float other = __shfl_xor(acc, 1);
    const float mx = fmaxf(acc, other);
    const float e  = __expf(acc - mx);
    const float eo = __expf(other - mx);
    out[t] = e / (e + eo);
}

extern "C" void kernel_launch(void* const* d_in, const int* in_sizes, int n_in,
                              void* d_out, int out_size, void* d_ws, size_t ws_size,
                              hipStream_t stream) {
    const float* x   = (const float*)d_in[0];
    const float* W1  = (const float*)d_in[1];
    const float* b1  = (const float*)d_in[2];
    const float* W2  = (const float*)d_in[3];
    const float* b2  = (const float*)d_in[4];
    const float* Wg1 = (const float*)d_in[5];
    const float* bg1 = (const float*)d_in[6];
    const float* Wg2 = (const float*)d_in[7];
    const float* bg2 = (const float*)d_in[8];
    const float* Wf  = (const float*)d_in[9];
    const float* bf  = (const float*)d_in[10];

    ushort* h2   = (ushort*)d_ws;                        // [B*N][80] bf16
    ushort* V1T  = h2  + (size_t)BB * NN * 80;           // [B][48][N] (ch40=1)
    float*  sq2  = (float*)(V1T + (size_t)BB * 48 * NN); // [B*N] (0.5|h2|^2)
    ushort* h3   = (ushort*)(sq2 + (size_t)BB * NN);     // [B*N][48]
    ushort* V2T  = h3  + (size_t)BB * NN * 48;           // [B][16][N] (ch8=1)
    float*  sq3  = (float*)(V2T + (size_t)BB * 16 * NN); // [B*N] (0.5|h3|^2)
    float*  meanb = sq3 + (size_t)BB * NN;               // [B*5] (+pad to 160)
    ushort* Wt1  = (ushort*)(meanb + 160);               // [160][320]
    ushort* Wt2  = Wt1 + (size_t)H1 * D_IN;              // [80][160]
    ushort* Wg1B = Wt2 + (size_t)H2 * H1;                // [48][96] plain
    float*  bg1P = (float*)(Wg1B + 48 * 96);             // [64]
    ushort* Wg2A = (ushort*)(bg1P + 64);                 // [32][48] (perm)
    float*  bg2P = (float*)(Wg2A + 32 * 48);             // [32]
    float*  pO   = bg2P + 32;                            // [512*2*2*16*256] f32
                                                         // (33.6 MB, reused by conv2)

    hipMemsetAsync(meanb, 0, BB * H4 * sizeof(float), stream);

    prep_weights_kernel<<<64, 256, 0, stream>>>(W1, W2, Wg1, bg1, Wg2, bg2,
                                                Wt1, Wt2, Wg1B, bg1P, Wg2A, bg2P);
    mlp_mfma_kernel<<<BB * NN / 64, 256, 0, stream>>>(x, Wt1, b1, Wt2, b2, Wg1B,
                                                      h2, V1T, sq2);
    attn_part_kernel<80, 64, 48, 2><<<BB * NN / 128 * 2, 256, 0, stream>>>(
        h2, V1T, sq2, pO);
    attn_combine_kernel<64, 48, 40, true, false, 0, 2><<<BB * NN / 128, 256, 0, stream>>>(
        pO, Wg2A, bg1P, h3, V2T, sq3, nullptr);
    attn_part_kernel<48, 32, 16, 2><<<BB * NN / 128 * 2, 256, 0, stream>>>(
        h3, V2T, sq3, pO);
    attn_combine_kernel<32, 16, 8, false, true, 5, 2><<<BB * NN / 128, 256, 0, stream>>>(
        pO, nullptr, bg2P, nullptr, nullptr, nullptr, meanb);
    final_kernel<<<1, 64, 0, stream>>>(meanb, Wf, bf, (float*)d_out);
}

// Round 9
// 253.423 us; speedup vs baseline: 1.1466x; 1.1466x over previous
//
#include <hip/hip_runtime.h>
#include <math.h>

#define BB 32
#define NN 2048
#define D_IN 320
#define H1 160
#define H2 80
#define H4 5

typedef __attribute__((ext_vector_type(8))) short short8;
typedef __attribute__((ext_vector_type(4))) short short4v;
typedef __attribute__((ext_vector_type(4))) float f32x4;
typedef __attribute__((ext_vector_type(16))) float f32x16;

__device__ inline ushort f2bf(float f) {
    union { float f; unsigned u; } v; v.f = f;
    unsigned r = v.u + 0x7fff + ((v.u >> 16) & 1);   // RNE
    return (ushort)(r >> 16);
}
__device__ inline float bf2f(ushort u) {
    union { float f; unsigned u; } v; v.u = ((unsigned)u) << 16;
    return v.f;
}
// pack 2 floats -> 2 bf16 in one dword (lo in low half): round-half-up + v_perm
__device__ inline unsigned pkbf(float hi, float lo) {
    union { float f; unsigned u; } a, b; a.f = hi; b.f = lo;
    return __builtin_amdgcn_perm(a.u + 0x8000u, b.u + 0x8000u, 0x07060302u);
}
// single-instruction pack: dst.lo = bf16(lo), dst.hi = bf16(hi)  (RNE)
__device__ inline unsigned cvtpk(float lo, float hi) {
    unsigned r;
    asm("v_cvt_pk_bf16_f32 %0, %1, %2" : "=v"(r) : "v"(lo), "v"(hi));
    return r;
}
// bare v_exp_f32: args here are always <= 0; big-negative flushes to 0 (wanted).
__device__ inline float fexp2(float x) {
    float r;
    asm("v_exp_f32 %0, %1" : "=v"(r) : "v"(x));
    return r;
}
union U2S { unsigned u[2]; short4v s; };
union U4S { unsigned u[4]; short8 s; short4v h[2]; };

#define LOG2E  1.44269504088896340736f
#define TWOL2E 2.88539008177792681472f

// ---------------------------------------------------------------------------
// Prep: bf16-transpose weights. Wt1[160][320], Wt2[80][160] (MLP B-operands).
// Wg1B[48][96]: plain B-operand layout for the mlp-epilogue V1' projection.
// Wg2A[32][48]: A-operand layout, phi-permuted, for conv1-epilogue V2'.
// bg1P[64], bg2P[32] zero-padded.
// ---------------------------------------------------------------------------
__global__ __launch_bounds__(256) void prep_weights_kernel(
    const float* __restrict__ W1, const float* __restrict__ W2,
    const float* __restrict__ Wg1, const float* __restrict__ bg1,
    const float* __restrict__ Wg2, const float* __restrict__ bg2,
    ushort* __restrict__ Wt1, ushort* __restrict__ Wt2,
    ushort* __restrict__ Wg1B, float* __restrict__ bg1P,
    ushort* __restrict__ Wg2A, float* __restrict__ bg2P)
{
    const int id0 = blockIdx.x * 256 + threadIdx.x;
    const int stride = gridDim.x * 256;
    for (int i = id0; i < H1 * D_IN; i += stride) {
        const int j = i / D_IN, c = i % D_IN;
        Wt1[i] = f2bf(W1[c * H1 + j]);
    }
    for (int i = id0; i < H2 * H1; i += stride) {
        const int j = i / H1, c = i % H1;
        Wt2[i] = f2bf(W2[c * H2 + j]);
    }
    for (int i = id0; i < 48 * 96; i += stride) {
        const int j = i / 96, c = i % 96;
        Wg1B[i] = (j < 40 && c < 80) ? f2bf(Wg1[c * 40 + j]) : (ushort)0;
    }
    for (int i = id0; i < 32 * 48; i += stride) {
        const int j = i / 48, c = i % 48;
        const int c4 = c & 15;
        const int pos = (c & ~15) + (c4 & 3) + (((c4 >> 3) & 1) << 2) + (((c4 >> 2) & 1) << 3);
        Wg2A[j * 48 + pos] = (j < 5 && c < 40) ? f2bf(Wg2[c * 5 + j]) : (ushort)0;
    }
    if (id0 < 64) bg1P[id0] = (id0 < 40) ? bg1[id0] : 0.f;
    if (id0 < 32) bg2P[id0] = (id0 < 5) ? bg2[id0] : 0.f;
}

// ---------------------------------------------------------------------------
// MFMA MLP: h2 = relu(relu(x@W1+b1)@W2+b2), XCD-swizzled.
// Computes the FOLDED conv1 value tensor V1' = h2 @ Wg1 -> V1T [b][48][N].
// h2 stored UNSCALED; sq2 = 0.5*|h2_bf16|^2 from the exact stored bits.
// ---------------------------------------------------------------------------
__global__ __launch_bounds__(256) void mlp_mfma_kernel(
    const float* __restrict__ x,
    const ushort* __restrict__ Wt1, const float* __restrict__ b1,
    const ushort* __restrict__ Wt2, const float* __restrict__ b2,
    const ushort* __restrict__ Wg1B,
    ushort* __restrict__ h2, ushort* __restrict__ V1T, float* __restrict__ sq2)
{
    constexpr int XST  = 72;
    constexpr int W1ST = 72;
    constexpr int H1ST = 168;
    constexpr int RST  = 104;   // h2 row-major stride for V1' A-frags

    __shared__ __attribute__((aligned(16))) ushort h1t[64 * H1ST];  // aliases xs
    __shared__ __attribute__((aligned(16))) ushort ws1[H1 * W1ST];  // aliases Tbuf
    __shared__ float b1s[H1];
    __shared__ float b2s[H2];

    ushort* xs = h1t;

    const int t = threadIdx.x;
    const int lane = t & 63, w = t >> 6;
    const int colid = lane & 15, quad = lane >> 4;
    const int i = blockIdx.x;
    const int b = ((i & 7) << 2) + ((i >> 3) & 3);
    const int n0 = (i >> 5) * 64;
    const int row0 = b * NN + n0;

    if (t < H1) b1s[t] = b1[t];
    if (t < H2) b2s[t] = b2[t];

    f32x4 c1[10];
    #pragma unroll
    for (int ns = 0; ns < 10; ++ns) c1[ns] = (f32x4){0.f, 0.f, 0.f, 0.f};

    float4 xr[4];
    short8 wr[5];
    {
        #pragma unroll
        for (int i2 = 0; i2 < 4; ++i2) {
            const int id = t + i2 * 256, row = id >> 4, c4 = id & 15;
            xr[i2] = *(const float4*)&x[(size_t)(row0 + row) * D_IN + c4 * 4];
        }
        #pragma unroll
        for (int i2 = 0; i2 < 5; ++i2) {
            const int id = t + i2 * 256, j = id >> 3, part = id & 7;
            wr[i2] = *(const short8*)&Wt1[j * D_IN + part * 8];
        }
    }

    for (int kc = 0; kc < 5; ++kc) {
        if (kc) __syncthreads();
        #pragma unroll
        for (int i2 = 0; i2 < 4; ++i2) {
            const int id = t + i2 * 256, row = id >> 4, c4 = id & 15;
            uint2 up;
            up.x = pkbf(xr[i2].y, xr[i2].x);
            up.y = pkbf(xr[i2].w, xr[i2].z);
            *(uint2*)&xs[row * XST + c4 * 4] = up;
        }
        #pragma unroll
        for (int i2 = 0; i2 < 5; ++i2) {
            const int id = t + i2 * 256, j = id >> 3, part = id & 7;
            *(short8*)&ws1[j * W1ST + part * 8] = wr[i2];
        }
        __syncthreads();
        if (kc < 4) {
            const int k0 = (kc + 1) * 64;
            #pragma unroll
            for (int i2 = 0; i2 < 4; ++i2) {
                const int id = t + i2 * 256, row = id >> 4, c4 = id & 15;
                xr[i2] = *(const float4*)&x[(size_t)(row0 + row) * D_IN + k0 + c4 * 4];
            }
            #pragma unroll
            for (int i2 = 0; i2 < 5; ++i2) {
                const int id = t + i2 * 256, j = id >> 3, part = id & 7;
                wr[i2] = *(const short8*)&Wt1[j * D_IN + k0 + part * 8];
            }
        }

        short8 af[2];
        #pragma unroll
        for (int kf = 0; kf < 2; ++kf)
            af[kf] = *(const short8*)&xs[(w * 16 + colid) * XST + kf * 32 + quad * 8];
        #pragma unroll
        for (int ns = 0; ns < 10; ++ns) {
            #pragma unroll
            for (int kf = 0; kf < 2; ++kf) {
                const short8 bf = *(const short8*)&ws1[(ns * 16 + colid) * W1ST + kf * 32 + quad * 8];
                c1[ns] = __builtin_amdgcn_mfma_f32_16x16x32_bf16(af[kf], bf, c1[ns], 0, 0, 0);
            }
        }
    }
    __syncthreads();                            // xs dead -> h1t reuse

    #pragma unroll
    for (int ns = 0; ns < 10; ++ns) {
        const float bj = b1s[ns * 16 + colid];
        #pragma unroll
        for (int r = 0; r < 4; ++r)
            h1t[(w * 16 + quad * 4 + r) * H1ST + ns * 16 + colid] =
                f2bf(fmaxf(c1[ns][r] + bj, 0.f));
    }
    __asm__ volatile("s_waitcnt lgkmcnt(0)" ::: "memory");  // wave-private rows

    short8 a2[5];
    #pragma unroll
    for (int kf = 0; kf < 5; ++kf)
        a2[kf] = *(const short8*)&h1t[(w * 16 + colid) * H1ST + kf * 32 + quad * 8];

    f32x4 c2[5];
    #pragma unroll
    for (int js = 0; js < 5; ++js) {
        f32x4 acc = (f32x4){0.f, 0.f, 0.f, 0.f};
        #pragma unroll
        for (int kf = 0; kf < 5; ++kf) {
            const short8 wb = *(const short8*)&Wt2[(js * 16 + colid) * H1 + kf * 32 + quad * 8];
            acc = __builtin_amdgcn_mfma_f32_16x16x32_bf16(a2[kf], wb, acc, 0, 0, 0);
        }
        c2[js] = acc;
    }
    __syncthreads();                            // h1t(a2 reads)/ws1 dead

    // ---- epilogue: h2 global (unscaled) + row-major LDS copy, rsq ----
    ushort* h2row = h1t;                        // [64][RST] row-major
    float rsq[4] = {0.f, 0.f, 0.f, 0.f};
    #pragma unroll
    for (int js = 0; js < 5; ++js) {
        const float bj = b2s[js * 16 + colid];
        #pragma unroll
        for (int r = 0; r < 4; ++r) {
            const ushort u = f2bf(fmaxf(c2[js][r] + bj, 0.f));
            const float vv = bf2f(u);
            rsq[r] += vv * vv;
            h2[(size_t)(row0 + w * 16 + quad * 4 + r) * 80 + js * 16 + colid] = u;
            h2row[(w * 16 + quad * 4 + r) * RST + js * 16 + colid] = u;
        }
    }
    {   // zero cols 80..95 (wave-private rows: t>>2 in [w*16, w*16+16))
        const int zr = t >> 2, zc = t & 3;
        *(short4v*)&h2row[zr * RST + 80 + zc * 4] = (short4v){0, 0, 0, 0};
    }
    __asm__ volatile("s_waitcnt lgkmcnt(0)" ::: "memory");  // wave-private rows

    // ---- V1' = h2 @ Wg1 (48 out, k padded to 96; Wg1B zero kills pad) ----
    short8 a3[3];
    #pragma unroll
    for (int kf = 0; kf < 3; ++kf)
        a3[kf] = *(const short8*)&h2row[(w * 16 + colid) * RST + kf * 32 + quad * 8];

    f32x4 c3[3];
    #pragma unroll
    for (int js = 0; js < 3; ++js) {
        f32x4 acc = (f32x4){0.f, 0.f, 0.f, 0.f};
        #pragma unroll
        for (int kf = 0; kf < 3; ++kf) {
            const short8 wb = *(const short8*)&Wg1B[(js * 16 + colid) * 96 + kf * 32 + quad * 8];
            acc = __builtin_amdgcn_mfma_f32_16x16x32_bf16(a3[kf], wb, acc, 0, 0, 0);
        }
        c3[js] = acc;
    }

    #pragma unroll
    for (int m = 1; m <= 8; m <<= 1)
        #pragma unroll
        for (int r = 0; r < 4; ++r) rsq[r] += __shfl_xor(rsq[r], m);
    if (colid == 0) {
        #pragma unroll
        for (int r = 0; r < 4; ++r)
            sq2[(size_t)row0 + w * 16 + quad * 4 + r] = rsq[r] * 0.5f;
    }

    // ---- transpose V1' -> V1T [b][48][N], ones row at 40 ----
    ushort* Tbuf = ws1;                         // [48][72]
    #pragma unroll
    for (int js = 0; js < 3; ++js)
        #pragma unroll
        for (int r = 0; r < 4; ++r)
            Tbuf[(js * 16 + colid) * 72 + w * 16 + quad * 4 + r] = f2bf(c3[js][r]);
    __syncthreads();
    const short8 ones8 = {16256, 16256, 16256, 16256, 16256, 16256, 16256, 16256};
    for (int id = t; id < 48 * 8; id += 256) {
        const int row = id >> 3, part = id & 7;
        const short8 val = (row == 40) ? ones8 : *(const short8*)&Tbuf[row * 72 + part * 8];
        *(short8*)&V1T[((size_t)b * 48 + row) * NN + n0 + part * 8] = val;
    }
}

// ---------------------------------------------------------------------------
// Flash-attention graph conv, 32x32x16 MFMA, 4 waves x 32 q = 128 q/block.
// V is the PRE-PROJECTED value tensor. SOFTWARE-PIPELINED across key tiles
// (R3-proven): exp/pack/PV of tile it-1 interleaves with the S-MFMA of tile
// it. S accumulator seeded with -0.5|q|^2-0.5|k|^2; p = exp2(st * 2log2e).
// CHANGE vs R3: the hot-loop p->bf16 pack uses v_cvt_pk_bf16_f32 (1 inst)
// instead of pkbf (3 insts) -> -32 VALU/tile/wave on the exp->PV chain.
// ---------------------------------------------------------------------------
template<int CK, int CV, int CVS, int ONES_CH, bool HAS_OUT, bool DO_MEAN, int C_OUT>
__global__ __launch_bounds__(256, 2) void attn_conv_kernel(
    const ushort* __restrict__ h, const ushort* __restrict__ hT,
    const float* __restrict__ sqg,
    const ushort* __restrict__ WtP, const float* __restrict__ biasP,
    ushort* __restrict__ ho, ushort* __restrict__ hoT, float* __restrict__ sqo,
    float* __restrict__ mean_out)
{
    constexpr int CF   = CK / 16;        // S-phase k-chunks (5 / 3)
    constexpr int CSV  = CV / 32;        // PV channel tiles (2 / 1)
    constexpr int KST  = CK + 8;         // 88 / 56
    constexpr int VST  = 64 + 8;         // 72
    constexpr int KPR  = CK / 8;
    constexpr int KTOT = 64 * KPR;
    constexpr int NK   = (KTOT + 255) / 256;
    constexpr int NV   = (CV * 8) / 256;
    constexpr int TST  = 136;
    constexpr int CS1  = ONES_CH / 32;
    constexpr int R1   = ((ONES_CH % 32) / 8) * 4 + (ONES_CH & 3);
    constexpr int BUFN = 64 * KST + CV * VST;
    constexpr int NIT  = NN / 64;        // 32 key tiles

    __shared__ __attribute__((aligned(16))) ushort ldsbuf[2][BUFN];
    __shared__ __attribute__((aligned(16))) float sqs[2][64];

    const int t = threadIdx.x;
    const int lane = t & 63, w = t >> 6;
    const int m32 = lane & 31, hl = lane >> 5;
    const int i = blockIdx.x;
    const int b = ((i & 7) << 2) + ((i >> 3) & 3);
    const int n0blk = (i >> 5) * 128;
    const int qrow = n0blk + w * 32 + m32;

    // Q B-operand frags
    short8 qf[CF];
    {
        const ushort* qr = h + ((size_t)b * NN + qrow) * CK;
        #pragma unroll
        for (int c = 0; c < CF; ++c)
            qf[c] = *(const short8*)&qr[c * 16 + hl * 8];
    }
    const float nsqn = -sqg[(size_t)b * NN + qrow];   // = -0.5|q|^2

    f32x16 o[CSV];
    #pragma unroll
    for (int cs = 0; cs < CSV; ++cs)
        #pragma unroll
        for (int r = 0; r < 16; ++r) o[cs][r] = 0.f;

    short8 kreg[NK], vreg[NV];
    float sqreg = 0.f;

    auto loadTile = [&](int n1) {
        const ushort* hsrc = h + ((size_t)b * NN + n1) * CK;
        #pragma unroll
        for (int i2 = 0; i2 < NK; ++i2) {
            const int id = t + i2 * 256;
            if (KTOT % 256 == 0 || id < KTOT)
                kreg[i2] = *(const short8*)&hsrc[id * 8];
        }
        #pragma unroll
        for (int i2 = 0; i2 < NV; ++i2) {
            const int id = t + i2 * 256, c = id >> 3, pt = id & 7;
            vreg[i2] = (c < CVS)
                ? *(const short8*)&hT[((size_t)b * CVS + c) * NN + n1 + pt * 8]
                : (short8){0, 0, 0, 0, 0, 0, 0, 0};
        }
        if (t < 64) sqreg = sqg[(size_t)b * NN + n1 + t];
    };
    auto stageTile = [&](int buf) {
        ushort* Kd = ldsbuf[buf];
        ushort* Vd = ldsbuf[buf] + 64 * KST;
        #pragma unroll
        for (int i2 = 0; i2 < NK; ++i2) {
            const int id = t + i2 * 256;
            if (KTOT % 256 == 0 || id < KTOT) {
                const int row = id / KPR, pt = id % KPR;
                *(short8*)&Kd[row * KST + pt * 8] = kreg[i2];
            }
        }
        #pragma unroll
        for (int i2 = 0; i2 < NV; ++i2) {
            const int id = t + i2 * 256, c = id >> 3, pt = id & 7;
            const int colb = ((pt >> 1) << 4) + ((pt & 1) << 2);  // phi baked in
            U4S vv; vv.s = vreg[i2];
            *(short4v*)&Vd[c * VST + colb]     = vv.h[0];
            *(short4v*)&Vd[c * VST + colb + 8] = vv.h[1];
        }
        if (t < 64) sqs[buf][t] = sqreg;
    };

    auto preloadK = [&](const ushort* Krow, short8 (&kf)[2][CF]) {
        #pragma unroll
        for (int T = 0; T < 2; ++T)
            #pragma unroll
            for (int c = 0; c < CF; ++c)
                kf[T][c] = *(const short8*)&Krow[(T * 32 + m32) * KST + c * 16 + hl * 8];
    };
    auto initST = [&](int cur, f32x16& s0, f32x16& s1) {
        #pragma unroll
        for (int g = 0; g < 4; ++g) {
            const f32x4 sm0 = *(const f32x4*)&sqs[cur][g * 8 + hl * 4];
            const f32x4 sm1 = *(const f32x4*)&sqs[cur][32 + g * 8 + hl * 4];
            #pragma unroll
            for (int r2 = 0; r2 < 4; ++r2) {
                s0[g * 4 + r2] = nsqn - sm0[r2];
                s1[g * 4 + r2] = nsqn - sm1[r2];
            }
        }
    };
    auto smfma = [&](short8 (&kf)[2][CF], f32x16& s0, f32x16& s1) {
        #pragma unroll
        for (int c = 0; c < CF; ++c) {
            s0 = __builtin_amdgcn_mfma_f32_32x32x16_bf16(kf[0][c], qf[c], s0, 0, 0, 0);
            s1 = __builtin_amdgcn_mfma_f32_32x32x16_bf16(kf[1][c], qf[c], s1, 0, 0, 0);
        }
    };
    auto preloadV = [&](const ushort* Vcol, short8 (&vf)[2][2][CSV]) {
        #pragma unroll
        for (int T = 0; T < 2; ++T)
            #pragma unroll
            for (int c = 0; c < 2; ++c)
                #pragma unroll
                for (int cs = 0; cs < CSV; ++cs)
                    vf[T][c][cs] = *(const short8*)&Vcol[(cs * 32 + m32) * VST + (T * 2 + c) * 16 + hl * 8];
    };
    auto expPV = [&](const f32x16& s0, const f32x16& s1, const short8 (&vf)[2][2][CSV]) {
        #pragma unroll
        for (int T = 0; T < 2; ++T) {
            const f32x16& st = T ? s1 : s0;
            float p[16];
            #pragma unroll
            for (int g = 0; g < 4; ++g)
                #pragma unroll
                for (int r2 = 0; r2 < 4; ++r2)
                    p[g * 4 + r2] = fexp2(st[g * 4 + r2] * TWOL2E);
            #pragma unroll
            for (int c = 0; c < 2; ++c) {
                U4S pk_;
                #pragma unroll
                for (int bq = 0; bq < 4; ++bq)
                    pk_.u[bq] = cvtpk(p[c * 8 + bq * 2], p[c * 8 + bq * 2 + 1]);
                #pragma unroll
                for (int cs = 0; cs < CSV; ++cs)
                    o[cs] = __builtin_amdgcn_mfma_f32_32x32x16_bf16(vf[T][c][cs], pk_.s, o[cs], 0, 0, 0);
            }
        }
    };

    loadTile(0);
    stageTile(0);
    __syncthreads();                           // buf0 visible
    loadTile(64);

    f32x16 stA0, stA1, stB0, stB1;
    short8 vfA[2][2][CSV], vfB[2][2][CSV];

    {   // ---- it = 0 (buf 0) ----
        short8 kf[2][CF];
        preloadK(ldsbuf[0], kf);
        initST(0, stA0, stA1);
        preloadV(ldsbuf[0] + 64 * KST, vfA);
        stageTile(1);                          // tile 1
        loadTile(128);                         // tile 2
        smfma(kf, stA0, stA1);
        __syncthreads();
    }

    #pragma unroll 1
    for (int k = 0; k < NIT / 2 - 1; ++k) {
        {   // ---- it = 1 + 2k (buf 1): build B, finish A ----
            short8 kf[2][CF];
            preloadK(ldsbuf[1], kf);
            initST(1, stB0, stB1);
            stageTile(0);                      // tile 2+2k
            loadTile((3 + 2 * k) * 64);        // tile 3+2k (always < NIT)
            smfma(kf, stB0, stB1);
            preloadV(ldsbuf[1] + 64 * KST, vfB);
            expPV(stA0, stA1, vfA);
            __syncthreads();
        }
        {   // ---- it = 2 + 2k (buf 0): build A, finish B ----
            short8 kf[2][CF];
            preloadK(ldsbuf[0], kf);
            initST(0, stA0, stA1);
            stageTile(1);                      // tile 3+2k
            if (k < NIT / 2 - 2) loadTile((4 + 2 * k) * 64);
            smfma(kf, stA0, stA1);
            preloadV(ldsbuf[0] + 64 * KST, vfA);
            expPV(stB0, stB1, vfB);
            __syncthreads();
        }
    }

    {   // ---- it = NIT-1 (buf 1): build B, finish A; no stage/load ----
        short8 kf[2][CF];
        preloadK(ldsbuf[1], kf);
        initST(1, stB0, stB1);
        smfma(kf, stB0, stB1);
        preloadV(ldsbuf[1] + 64 * KST, vfB);
        expPV(stA0, stA1, vfA);
        __syncthreads();
    }
    expPV(stB0, stB1, vfB);                    // drain pipeline

    // denominator from the ones-channel accumulator (lane hl=0 holds it)
    float rsv = (hl == 0) ? o[CS1][R1] : 0.f;
    rsv += __shfl_xor(rsv, 32);
    const float rinv = 1.f / rsv;

    if constexpr (DO_MEAN) {
        // channels 0..3 live at hl=0 regs 0..3; channel 4 at hl=1 reg 0
        float msum[4];
        #pragma unroll
        for (int r2 = 0; r2 < 4; ++r2)
            msum[r2] = fmaxf(o[0][r2] * rinv + biasP[hl * 4 + r2], 0.f);
        #pragma unroll
        for (int s = 1; s <= 16; s <<= 1)
            #pragma unroll
            for (int r2 = 0; r2 < 4; ++r2) msum[r2] += __shfl_xor(msum[r2], s);
        if (m32 == 0) {
            if (hl == 0) {
                #pragma unroll
                for (int r2 = 0; r2 < 4; ++r2)
                    atomicAdd(&mean_out[b * C_OUT + r2], msum[r2] * (1.f / NN));
            } else {
                atomicAdd(&mean_out[b * C_OUT + 4], msum[0] * (1.f / NN));
            }
        }
    }

    if constexpr (HAS_OUT) {
        // O is ALREADY projected (40 ch). h3 = relu(O*rinv + b); zero pads.
        float vv[CSV][16];
        float rsq = 0.f;
        #pragma unroll
        for (int cs = 0; cs < CSV; ++cs) {
            #pragma unroll
            for (int g = 0; g < 4; ++g) {
                const int jb = cs * 32 + g * 8 + hl * 4;
                const f32x4 bv = *(const f32x4*)&biasP[jb];
                float v[4];
                #pragma unroll
                for (int r2 = 0; r2 < 4; ++r2) {
                    float val = fmaxf(o[cs][g * 4 + r2] * rinv + bv[r2], 0.f);
                    if (cs == CS1 && g * 4 + r2 == R1) val = 0.f;  // ones slot
                    v[r2] = val;
                    vv[cs][g * 4 + r2] = val;
                }
                if (jb < 48) {                 // h3 stored at stride 48
                    U2S uo;
                    uo.u[0] = pkbf(v[1], v[0]);
                    uo.u[1] = pkbf(v[3], v[2]);
                    *(short4v*)&ho[((size_t)b * NN + qrow) * 48 + jb] = uo.s;
                    #pragma unroll
                    for (int r2 = 0; r2 < 4; ++r2) {
                        const float vs = bf2f((ushort)(uo.u[r2 >> 1] >> ((r2 & 1) * 16)));
                        rsq += vs * vs;
                    }
                }
            }
        }
        const float rsq2 = rsq + __shfl_xor(rsq, 32);
        if (hl == 0) sqo[(size_t)b * NN + qrow] = rsq2 * 0.5f;

        // V2' = h3 @ Wg2 (phi-consistent frags)
        short8 ob2[3];
        #pragma unroll
        for (int cc = 0; cc < 3; ++cc) {
            const int cs = cc >> 1, c2 = cc & 1;
            U4S ob_;
            #pragma unroll
            for (int bq = 0; bq < 4; ++bq)
                ob_.u[bq] = pkbf(vv[cs][c2 * 8 + bq * 2 + 1], vv[cs][c2 * 8 + bq * 2]);
            ob2[cc] = ob_.s;
        }
        f32x16 acc;
        #pragma unroll
        for (int r = 0; r < 16; ++r) acc[r] = 0.f;
        #pragma unroll
        for (int cc = 0; cc < 3; ++cc) {
            const short8 wa = *(const short8*)&WtP[(size_t)m32 * 48 + cc * 16 + hl * 8];
            acc = __builtin_amdgcn_mfma_f32_32x32x16_bf16(wa, ob2[cc], acc, 0, 0, 0);
        }

        // transposed store: V2T[b][16][n]; rows 0..4 = V2', 8 = ones, rest 0
        ushort* Tbuf = (ushort*)ldsbuf;        // [16][TST]
        #pragma unroll
        for (int g = 0; g < 2; ++g)
            #pragma unroll
            for (int r2 = 0; r2 < 4; ++r2)
                Tbuf[(g * 8 + hl * 4 + r2) * TST + w * 32 + m32] = f2bf(acc[g * 4 + r2]);
        __syncthreads();
        const short8 ones8 = {16256, 16256, 16256, 16256, 16256, 16256, 16256, 16256};
        {
            const int row = t >> 4, part = t & 15;   // 16 rows x 16 parts = 256
            const short8 val = (row == 8) ? ones8
                             : *(const short8*)&Tbuf[row * TST + part * 8];
            *(short8*)&hoT[((size_t)b * 16 + row) * NN + n0blk + part * 8] = val;
        }
    }
}

// ---------------------------------------------------------------------------
// Final classifier + softmax over 2 logits.
// ---------------------------------------------------------------------------
__global__ __launch_bounds__(64) void final_kernel(
    const float* __restrict__ mean, const float* __restrict__ Wf,
    const float* __restrict__ bf, float* __restrict__ out)
{
    const int t = threadIdx.x;
    const int b = t >> 1, k = t & 1;
    float acc = bf[k];
    #pragma unroll
    for (int c = 0; c < H4; ++c) acc += mean[b * H4 + c] * Wf[c * 2 + k];
    const float other = __shfl_xor(acc, 1);
    const float mx = fmaxf(acc, other);
    const float e  = __expf(acc - mx);
    const float eo = __expf(other - mx);
    out[t] = e / (e + eo);
}

extern "C" void kernel_launch(void* const* d_in, const int* in_sizes, int n_in,
                              void* d_out, int out_size, void* d_ws, size_t ws_size,
                              hipStream_t stream) {
    const float* x   = (const float*)d_in[0];
    const float* W1  = (const float*)d_in[1];
    const float* b1  = (const float*)d_in[2];
    const float* W2  = (const float*)d_in[3];
    const float* b2  = (const float*)d_in[4];
    const float* Wg1 = (const float*)d_in[5];
    const float* bg1 = (const float*)d_in[6];
    const float* Wg2 = (const float*)d_in[7];
    const float* bg2 = (const float*)d_in[8];
    const float* Wf  = (const float*)d_in[9];
    const float* bf  = (const float*)d_in[10];

    ushort* h2   = (ushort*)d_ws;                        // [B*N][80] bf16
    ushort* V1T  = h2  + (size_t)BB * NN * 80;           // [B][48][N] (ch40=1)
    float*  sq2  = (float*)(V1T + (size_t)BB * 48 * NN); // [B*N] (0.5|h2|^2)
    ushort* h3   = (ushort*)(sq2 + (size_t)BB * NN);     // [B*N][48]
    ushort* V2T  = h3  + (size_t)BB * NN * 48;           // [B][16][N] (ch8=1)
    float*  sq3  = (float*)(V2T + (size_t)BB * 16 * NN); // [B*N] (0.5|h3|^2)
    float*  meanb = sq3 + (size_t)BB * NN;               // [B*5] (+pad to 160)
    ushort* Wt1  = (ushort*)(meanb + 160);               // [160][320]
    ushort* Wt2  = Wt1 + (size_t)H1 * D_IN;              // [80][160]
    ushort* Wg1B = Wt2 + (size_t)H2 * H1;                // [48][96] plain
    float*  bg1P = (float*)(Wg1B + 48 * 96);             // [64]
    ushort* Wg2A = (ushort*)(bg1P + 64);                 // [32][48] (perm)
    float*  bg2P = (float*)(Wg2A + 32 * 48);             // [32]

    hipMemsetAsync(meanb, 0, BB * H4 * sizeof(float), stream);

    prep_weights_kernel<<<64, 256, 0, stream>>>(W1, W2, Wg1, bg1, Wg2, bg2,
                                                Wt1, Wt2, Wg1B, bg1P, Wg2A, bg2P);
    mlp_mfma_kernel<<<BB * NN / 64, 256, 0, stream>>>(x, Wt1, b1, Wt2, b2, Wg1B,
                                                      h2, V1T, sq2);
    attn_conv_kernel<80, 64, 48, 40, true,  false, 0><<<BB * NN / 128, 256, 0, stream>>>(
        h2, V1T, sq2, Wg2A, bg1P, h3, V2T, sq3, nullptr);
    attn_conv_kernel<48, 32, 16, 8,  false, true,  5><<<BB * NN / 128, 256, 0, stream>>>(
        h3, V2T, sq3, nullptr, bg2P, nullptr, nullptr, nullptr, meanb);
    final_kernel<<<1, 64, 0, stream>>>(meanb, Wf, bf, (float*)d_out);
}